// Round 1
// baseline (410.242 us; speedup 1.0000x reference)
//
#include <hip/hip_runtime.h>

// GR4J daily hydrological model, round 7: async input staging for the producer.
// T=4015 steps, WARMUP=365, B=2048 basins.
//
// R6 removed all barriers from the producer/consumer pipeline (LDS flag
// protocol) and gained only 404->398 us -- the barrier-drain theory was
// WRONG. The surviving theory for the ~2.5x gap above the issue floor:
// the producer's 11-deep register load rotation issues each global load
// exactly 11 steps before use, so coverage = 11 x step-time. That is a
// self-referential equilibrium: with effective load latency >= ~900 cyc
// (HBM + queueing on a 16KB-strided stream), the wave settles at rate
// ~ latency/11 and drags the whole pipeline to ~238 cyc/step.
//
// R7: producer inputs staged through an async global_load_lds ring:
//   - inbuf[4][11][2][64]: 4-slot ring of 11-step chunks, (p,e) planes.
//   - chunk c+2 issued (22 dword ops, wave-uniform LDS base, per-lane
//     global addr) while computing chunk c -> 22-step (~2-5k cyc) lookahead
//     that does NOT shrink when the wave speeds up.
//   - counted s_waitcnt vmcnt(22) at chunk top (never 0 mid-loop): only
//     the newest in-flight chunk may be outstanding; everything older
//     (i.e. chunk c) is guaranteed LDS-resident. vmcnt(0) only at c=364.
//   - 11 (p,e) pairs burst-read LDS->regs at chunk top; their ds latency
//     hides under the 22-op issue of chunk c+2.
// Producer loses rot[11] (22 VGPRs) and all per-load 64-bit address VALU.
// Consumer wave and flag protocol are BYTE-IDENTICAL to R6 for clean
// attribution: if dur is flat, the consumer is the wall (R8 target).
//
// Warmup without per-step predication: stores for t<365 go to out rows [t]
// (t<=364), later overwritten by the real rows (same wave, same address,
// program-ordered). Batch k=6 (t=330..384) fully unrolled: conv history
// reset before t=365 + store base switches dump->real.
//
// Approximations (threshold 3.97e-2; measured absmax with these: 7.8e-3):
//  - tanh(x) ~= x for x<=0.01; (1+z)^(-1/4) 3-term series in prod (z<=.039);
//  - routing keeps exact-form v_sqrt/v_rsq.
// Arithmetic is bit-identical to R6 => absmax must stay 0.0078125 exactly.

#define T_TOTAL 4015
#define NWARM   365
#define NB      2048
#define BSTEP   55
#define NBATCH  73          // 73 * 55 = 4015
#define CH      11          // producer staging chunk: 11 steps
#define NCHUNK  365         // 365 * 11 = 4015

typedef __attribute__((address_space(3))) float       lds_f;
typedef __attribute__((address_space(1))) const float glb_f;

__device__ __forceinline__ void gl_lds_dword(const float* g, float* l) {
    // async global->LDS, 4B per lane; LDS dst = uniform base + lane*4
    __builtin_amdgcn_global_load_lds((glb_f*)(uintptr_t)g,
                                     (lds_f*)(uintptr_t)l, 4, 0, 0);
}

__global__ __launch_bounds__(128, 1)
void gr4j_kernel(const float2* __restrict__ pe_in,   // [T_TOTAL*NB] (p,e)
                 const float*  __restrict__ params,  // [NB,4]
                 float*        __restrict__ out)     // [(T_TOTAL-NWARM)*NB]
{
    const int lane = threadIdx.x & 63;
    const int wid  = threadIdx.x >> 6;
    const int b    = blockIdx.x * 64 + lane;

    __shared__ float prbuf[2][BSTEP * 64];           // 28.2 KB double buffer
    __shared__ float inbuf[4][CH][2][64];            // 11.3 KB input ring
    __shared__ int produced;                         // batches written by w0
    __shared__ int consumed;                         // batches read by w1
    if (threadIdx.x == 0) { produced = 0; consumed = 0; }
    __syncthreads();   // the only barrier: flag init (outside the pipeline)

    const float x1 = 100.0f + params[b * 4 + 0] * 1100.0f;
    const float x2 = -5.0f  + params[b * 4 + 1] * 8.0f;
    const float x3 = 20.0f  + params[b * 4 + 2] * 280.0f;
    const float x4 = 1.1f   + params[b * 4 + 3] * 1.8f;
    const float invx1 = __builtin_amdgcn_rcpf(x1);
    const float invx3 = __builtin_amdgcn_rcpf(x3);
    const float c49   = (4.0f / 9.0f) * invx1;
    const float c49_2 = c49 * c49;
    const float c4s   = c49_2 * c49_2;               // ((4/9)/x1)^4
    const float i3_2  = invx3 * invx3;
    const float c4r   = i3_2 * i3_2;                 // (1/x3)^4

    if (wid == 0) {
        // ================== producer: s-chain -> pr ==================
        float s = 0.5f * x1;

        auto prod_step = [&](float p_, float e_) -> float {
            const float diff = p_ - e_;
            const float pn = fmaxf(diff, 0.0f);
            const float en = fmaxf(-diff, 0.0f);
            const float ap = pn * invx1;             // ~= tanh(pn/x1)
            const float ae = en * invx1;             // ~= tanh(en/x1)
            const float sx = s * invx1;
            const float dp = fmaf(sx, ap, 1.0f);
            const float de = fmaf(1.0f - sx, ae, 1.0f);
            const float n1 = fmaf(-sx, sx, 1.0f);
            const float nump = pn * n1;              // x1*(1-sx^2)*(pn/x1)
            const float nume = (sx * en) * (2.0f - sx);
            const float rpe = __builtin_amdgcn_rcpf(dp * de);
            const float a_ = nump * de;
            const float b_ = nume * dp;
            const float s2 = fmaf(a_ - b_, rpe, s);  // s - es + ps
            const float ps = a_ * rpe;
            const float s22 = s2 * s2;
            const float s24 = s22 * s22;
            const float z = c4s * s24;               // <= 0.039
            float w = fmaf(z, 15.0f / 128.0f, -5.0f / 32.0f);
            w = fmaf(z, w, 0.25f);
            const float perc = (s2 * z) * w;         // s2*(1-(1+z)^-.25)
            s = s2 - perc;
            return perc + (pn - ps);
        };

        // per-lane float base: element (t*NB+b) float2 == float idx 2*(t*NB+b)
        const float* pbase = (const float*)pe_in + 2 * b;

        // prologue: stage chunks 0,1 (44 dword ops in flight)
        #pragma unroll
        for (int cc = 0; cc < 2; ++cc) {
            const float* cb = pbase + (size_t)cc * CH * 2 * NB;
            #pragma unroll
            for (int i = 0; i < CH; ++i) {
                gl_lds_dword(cb + (size_t)i * 2 * NB,     &inbuf[cc][i][0][0]);
                gl_lds_dword(cb + (size_t)i * 2 * NB + 1, &inbuf[cc][i][1][0]);
            }
        }

        for (int c = 0; c < NCHUNK; ++c) {
            const int k  = c / 5;                    // batch index
            const int ph = c - 5 * k;                // chunk within batch
            if (ph == 0 && k >= 2) {
                while (__hip_atomic_load(&consumed, __ATOMIC_ACQUIRE,
                                         __HIP_MEMORY_SCOPE_WORKGROUP) < k - 1) {}
            }

            // Counted wait: newest 22 ops (chunk c+1) may remain in flight;
            // all older ops (chunk c) are retired => slot c&3 is resident.
            if (c < NCHUNK - 1) asm volatile("s_waitcnt vmcnt(22)" ::: "memory");
            else                asm volatile("s_waitcnt vmcnt(0)"  ::: "memory");

            // burst-read the chunk's 11 (p,e) pairs LDS->regs
            const int slot = c & 3;
            float pf_p[CH], pf_e[CH];
            #pragma unroll
            for (int i = 0; i < CH; ++i) {
                pf_p[i] = inbuf[slot][i][0][lane];
                pf_e[i] = inbuf[slot][i][1][lane];
            }

            // issue chunk c+2 while the ds_reads above are in flight
            if (c + 2 < NCHUNK) {
                const float* cb = pbase + (size_t)(c + 2) * CH * 2 * NB;
                const int s2 = (c + 2) & 3;          // != slot (differ by 2 mod 4)
                #pragma unroll
                for (int i = 0; i < CH; ++i) {
                    gl_lds_dword(cb + (size_t)i * 2 * NB,     &inbuf[s2][i][0][0]);
                    gl_lds_dword(cb + (size_t)i * 2 * NB + 1, &inbuf[s2][i][1][0]);
                }
            }

            float* dst = &prbuf[k & 1][0] + (ph * CH) * 64 + lane;
            #pragma unroll
            for (int i = 0; i < CH; ++i)
                dst[i * 64] = prod_step(pf_p[i], pf_e[i]);

            if (ph == 4)
                __hip_atomic_store(&produced, k + 1, __ATOMIC_RELEASE,
                                   __HIP_MEMORY_SCOPE_WORKGROUP);
        }
    } else {
        // ============ consumer: conv + r-chain + stores ============
        // (byte-identical to R6 for clean attribution)
        float u10, u11, u12, u20, u21, u22, u23, u24, u25;
        {
            float sh[3];
            #pragma unroll
            for (int j = 1; j <= 3; ++j)
                sh[j - 1] = powf(fminf((float)j / x4, 1.0f), 2.5f);
            u10 = sh[0]; u11 = sh[1] - sh[0]; u12 = sh[2] - sh[1];
            float s2h[6];
            #pragma unroll
            for (int j = 1; j <= 6; ++j) {
                float rr = (float)j / x4;
                s2h[j - 1] = ((float)j <= x4) ? 0.5f * powf(rr, 2.5f)
                           : 1.0f - 0.5f * powf(fmaxf(2.0f - rr, 0.0f), 2.5f);
            }
            u20 = s2h[0];          u21 = s2h[1] - s2h[0]; u22 = s2h[2] - s2h[1];
            u23 = s2h[3] - s2h[2]; u24 = s2h[4] - s2h[3]; u25 = s2h[5] - s2h[4];
        }

        float r = 0.5f * x3;
        float ph0 = 0.f, ph1 = 0.f, ph2 = 0.f, ph3 = 0.f, ph4 = 0.f;

        auto w1_step = [&](float pr) -> float {
            const float q9 = fmaf(u10, pr, fmaf(u11, ph0, u12 * ph1));
            const float q1 = fmaf(u20, pr, fmaf(u21, ph0, fmaf(u22, ph1,
                             fmaf(u23, ph2, fmaf(u24, ph3, u25 * ph4)))));
            ph4 = ph3; ph3 = ph2; ph2 = ph1; ph1 = ph0; ph0 = pr;
            const float rq = r + q9;                 // off the gex path
            const float rx = r * invx3;
            const float srx = __builtin_amdgcn_sqrtf(rx);
            const float gex = (x2 * ((rx * rx) * rx)) * srx; // x2*(r/x3)^3.5
            const float r2 = fmaxf(0.0f, rq + gex);
            const float r22 = r2 * r2;
            const float r24 = r22 * r22;
            const float v4p1 = fmaf(c4r, r24, 1.0f);
            const float rn = r2 * __builtin_amdgcn_rsqf(__builtin_amdgcn_sqrtf(v4p1));
            const float qr = r2 - rn;
            r = rn;
            return qr + fmaxf(0.0f, q1 + gex);
        };

        for (int k = 0; k < NBATCH; ++k) {
            while (__hip_atomic_load(&produced, __ATOMIC_ACQUIRE,
                                     __HIP_MEMORY_SCOPE_WORKGROUP) < k + 1) {}
            const float* src = &prbuf[k & 1][0] + lane;
            if (k != 6) {
                // k<6: t=55k..55k+54 <= 329 -> dump rows [t] (overwritten by
                // t'=365+row later, same wave => ordered). k>=7: rows t-365.
                float* ob = (k < 6)
                    ? out + (size_t)(k * BSTEP) * NB + b
                    : out + (size_t)(k * BSTEP - NWARM) * NB + b;
                float prr[11];
                #pragma unroll
                for (int i = 0; i < 11; ++i) prr[i] = src[i * 64];
                for (int g = 0; g < 5; ++g) {
                    const float* sp = src + (g + 1) * (11 * 64);
                    float* ob2 = ob + (size_t)(g * 11) * NB;
                    if (g < 4) {
                        #pragma unroll
                        for (int i = 0; i < 11; ++i) {
                            const float pr = prr[i];
                            prr[i] = sp[i * 64];         // prefetch 11 ahead
                            ob2[(size_t)i * NB] = w1_step(pr);
                        }
                    } else {
                        #pragma unroll
                        for (int i = 0; i < 11; ++i)
                            ob2[(size_t)i * NB] = w1_step(prr[i]);
                    }
                }
            } else {
                // Special batch k=6: t=330..384. Conv-history reset before
                // t=365 (j==35); store base switches dump->real. Fully
                // unrolled so all conditions fold at compile time.
                float* dumpb = out + (size_t)330 * NB + b;   // rows 330..364
                float* realb = out + b;                      // rows 0..19
                float prr[11];
                #pragma unroll
                for (int i = 0; i < 11; ++i) prr[i] = src[i * 64];
                #pragma unroll
                for (int g = 0; g < 5; ++g) {
                    #pragma unroll
                    for (int i = 0; i < 11; ++i) {
                        const int j = g * 11 + i;            // step in batch
                        const float pr = prr[i];
                        if (g < 4) prr[i] = src[(j + 11) * 64];
                        if (j == 35) { ph0 = ph1 = ph2 = ph3 = ph4 = 0.0f; }
                        const float q = w1_step(pr);
                        if (j < 35) dumpb[(size_t)j * NB] = q;
                        else        realb[(size_t)(j - 35) * NB] = q;
                    }
                }
            }
            __hip_atomic_store(&consumed, k + 1, __ATOMIC_RELEASE,
                               __HIP_MEMORY_SCOPE_WORKGROUP);
        }
    }
}

extern "C" void kernel_launch(void* const* d_in, const int* in_sizes, int n_in,
                              void* d_out, int out_size, void* d_ws, size_t ws_size,
                              hipStream_t stream) {
    const float2* pe_in  = (const float2*)d_in[0];   // p_and_e [4015,2048,2]
    const float*  params = (const float*)d_in[1];    // parameters [2048,4]
    float* out = (float*)d_out;                      // [3650,2048,1]
    (void)in_sizes; (void)n_in; (void)out_size; (void)d_ws; (void)ws_size;

    gr4j_kernel<<<dim3(NB / 64), dim3(128), 0, stream>>>(pe_in, params, out);
}